// Round 11
// baseline (9396.782 us; speedup 1.0000x reference)
//
#include <hip/hip_runtime.h>

#define TT 2048
#define BB 8
#define DD 1024
#define HH 1024
#define NBLK 64

typedef unsigned int u32;
typedef unsigned short u16;
typedef unsigned long long u64;
typedef float f32x4 __attribute__((ext_vector_type(4)));
typedef _Float16 f16x8 __attribute__((ext_vector_type(8)));

static __device__ __forceinline__ u32 f16bits(float x) {
    _Float16 h = (_Float16)x;
    u16 r;
    __builtin_memcpy(&r, &h, 2);
    return (u32)r;
}

// fast tanh: sign(x) * (1 - e^{-2|x|}) / (1 + e^{-2|x|}), exp2-based
static __device__ __forceinline__ float fast_tanh(float x) {
    const float ax = __builtin_fabsf(x);
    const float e = __builtin_amdgcn_exp2f(ax * -2.885390082f);
    const float r = (1.0f - e) * __builtin_amdgcn_rcpf(1.0f + e);
    return __builtin_copysignf(r, x);
}

// ---------------- sentinel zeroing (every launch: no cross-call state) ----------------
__global__ __launch_bounds__(64) void clear_sent_kernel(u32* sent) {
    __hip_atomic_store(&sent[threadIdx.x], 0u, __ATOMIC_RELAXED, __HIP_MEMORY_SCOPE_AGENT);
}

// ---------------- fused projection GEMMs via MFMA fp16 (unchanged) ----------------
__global__ __launch_bounds__(256) void proj_kernel(
    const float* __restrict__ x, const float* __restrict__ Wx,
    const float* __restrict__ Wd, const float* __restrict__ bias,
    const float* __restrict__ bdel, float* __restrict__ xw_out,
    float* __restrict__ decay_out)
{
    __shared__ __align__(16) _Float16 xs[64][40];
    __shared__ __align__(16) _Float16 wxs[64][40];
    __shared__ __align__(16) _Float16 wds[64][40];

    const int tid = threadIdx.x;
    const int bm = blockIdx.y * 64;
    const int bn = blockIdx.x * 64;
    const int w = tid >> 6, l = tid & 63;
    const int ar = l & 15, kg = l >> 4;
    const int srow = tid >> 2, scol = (tid & 3) * 8;

    f32x4 accx[4], accd[4];
#pragma unroll
    for (int ct = 0; ct < 4; ++ct) {
        accx[ct] = (f32x4){0.f, 0.f, 0.f, 0.f};
        accd[ct] = (f32x4){0.f, 0.f, 0.f, 0.f};
    }

    for (int k0 = 0; k0 < DD; k0 += 32) {
        const float* xp = &x[(size_t)(bm + srow) * DD + k0 + scol];
        const float* wxp = &Wx[(size_t)(bn + srow) * DD + k0 + scol];
        const float* wdp = &Wd[(size_t)(bn + srow) * DD + k0 + scol];
        f32x4 a0 = *(const f32x4*)xp,  a1 = *(const f32x4*)(xp + 4);
        f32x4 b0 = *(const f32x4*)wxp, b1 = *(const f32x4*)(wxp + 4);
        f32x4 c0 = *(const f32x4*)wdp, c1 = *(const f32x4*)(wdp + 4);
        f16x8 ha, hb_, hc;
#pragma unroll
        for (int e = 0; e < 4; ++e) {
            ha[e] = (_Float16)a0[e];  ha[e + 4] = (_Float16)a1[e];
            hb_[e] = (_Float16)b0[e]; hb_[e + 4] = (_Float16)b1[e];
            hc[e] = (_Float16)c0[e];  hc[e + 4] = (_Float16)c1[e];
        }
        __syncthreads();
        *(f16x8*)&xs[srow][scol] = ha;
        *(f16x8*)&wxs[srow][scol] = hb_;
        *(f16x8*)&wds[srow][scol] = hc;
        __syncthreads();

        const f16x8 af = *(const f16x8*)&xs[w * 16 + ar][kg * 8];
#pragma unroll
        for (int ct = 0; ct < 4; ++ct) {
            const f16x8 bfx = *(const f16x8*)&wxs[ct * 16 + ar][kg * 8];
            const f16x8 bfd = *(const f16x8*)&wds[ct * 16 + ar][kg * 8];
            accx[ct] = __builtin_amdgcn_mfma_f32_16x16x32_f16(af, bfx, accx[ct], 0, 0, 0);
            accd[ct] = __builtin_amdgcn_mfma_f32_16x16x32_f16(af, bfd, accd[ct], 0, 0, 0);
        }
    }

#pragma unroll
    for (int ct = 0; ct < 4; ++ct) {
        const int col = bn + ct * 16 + ar;
        const float bx = bias[col];
        const float bd = bdel[col];
#pragma unroll
        for (int jj = 0; jj < 4; ++jj) {
            const int row = bm + w * 16 + kg * 4 + jj;
            xw_out[(size_t)row * HH + col] = accx[ct][jj] + bx;
            decay_out[(size_t)row * HH + col] = 1.0f / (1.0f + expf(accd[ct][jj] + bd));
        }
    }
}

// ---------------- sequential scan: batch-filled MFMA columns + sentinel protocol ----------------
// 64 blocks x 512 threads (8 waves). Block j owns channels [j*16,+16) x ALL 8
// batches -> B operand holds 8 batches' h in 8 MFMA columns (vs 16x-wasted
// matvec): MFMAs/CU/step 256 -> 32, killing R8's ~1242-cyc matrix-pipe convoy.
// Protocol (2-hop): producers store raw fp16 h (1 packed u32 per lane of wave 7),
// s_waitcnt vmcnt(0) (release: data ACK'd at IF$ before flag), lane0 stores
// sent[j]=t+1. Consumers: wave 0 polls all 64 sentinels (lane=block, 4B each,
// staggered double-slot), barrier, then every wave bulk-loads its B-frags
// straight from IF$ into VGPRs (4x dwordx4 sc0 sc1, no retry, no LDS staging).
// Cross-wave K-reduce via red[8][8][20] + 1 barrier; single red buffer is safe:
// our own sentinel (stored after wave 7's red-reads of t) gates every wave's
// red-writes of t+1 via wave 0's poll. hdata ping-pong safe: our step-t B-loads
// require all sentinels(t-1), so every block finished reading h(t-2) before we
// store h(t) over it.
__global__ __launch_bounds__(512) void scan_kernel(
    const float* __restrict__ h0, const float* __restrict__ R,
    const float* __restrict__ decay, float* __restrict__ out,
    u16* __restrict__ hdata, u32* __restrict__ sent)
{
    __shared__ float red[8][8][20];   // [wave][batch][chloc(16)+pad] partials, 5 KB

    const int tid = threadIdx.x;
    const int w = tid >> 6, l = tid & 63;
    const int ar = l & 15, kg = l >> 4;
    const int j = blockIdx.x;        // channel block: [j*16, +16)
    const int bcol = l & 7;          // B batch column (cols 8-15 duplicate 0-7)

    // ---- one-time A fragments: R[j*16+ar][w*128 + s*32 + kg*8 ..], 16 VGPRs ----
    f16x8 afrag[4];
#pragma unroll
    for (int s = 0; s < 4; ++s) {
        const float* rp = &R[(size_t)(j * 16 + ar) * HH + w * 128 + s * 32 + kg * 8];
        const f32x4 r0 = *(const f32x4*)rp;
        const f32x4 r1 = *(const f32x4*)(rp + 4);
        f16x8 a;
#pragma unroll
        for (int e = 0; e < 4; ++e) { a[e] = (_Float16)r0[e]; a[e + 4] = (_Float16)r1[e]; }
        afrag[s] = a;
    }

    // ---- wave 7 = epilogue/producer: lane l -> batch eb, channel pair gch,gch+1 ----
    const int eb = l >> 3, ec = (l & 7) * 2;
    const int gch = j * 16 + ec;
    float hp0 = 0.f, hp1 = 0.f, xw0 = 0.f, xw1 = 0.f, dc0 = 0.f, dc1 = 0.f;
    if (w == 7) {
        hp0 = h0[(size_t)eb * HH + gch];
        hp1 = h0[(size_t)eb * HH + gch + 1];
        const float2 xv = *(const float2*)&out[(size_t)eb * HH + gch];   // row 0 = xw(0)
        const float2 dv = *(const float2*)&decay[(size_t)eb * HH + gch];
        xw0 = xv.x; xw1 = xv.y; dc0 = dv.x; dc1 = dv.y;
    }

    for (int t = 0; t < TT; ++t) {
        // ---- wave 0: poll all 64 sentinels (lane = source block) ----
        if (t > 0 && w == 0) {
            const u64 sp = (u64)(sent + l);
            const u32 tv = (u32)t;
            u32 sA, sB;
            asm volatile("global_load_dword %0, %1, off sc0 sc1" : "=v"(sA) : "v"(sp));
            __builtin_amdgcn_s_sleep(4);
            asm volatile("global_load_dword %0, %1, off sc0 sc1" : "=v"(sB) : "v"(sp));
            while (true) {
                asm volatile("s_waitcnt vmcnt(1)" ::: "memory");
                __builtin_amdgcn_sched_barrier(0);
                if (sA >= tv) break;
                asm volatile("global_load_dword %0, %1, off sc0 sc1" : "=v"(sA) : "v"(sp));
                asm volatile("s_waitcnt vmcnt(1)" ::: "memory");
                __builtin_amdgcn_sched_barrier(0);
                if (sB >= tv) break;
                asm volatile("global_load_dword %0, %1, off sc0 sc1" : "=v"(sB) : "v"(sp));
            }
            asm volatile("s_waitcnt vmcnt(0)" ::: "memory");
            __builtin_amdgcn_sched_barrier(0);
        }
        __syncthreads();   // barrier 1: all sources' data globally visible

        // ---- prefetch NEXT step's xw/decay (wave 7; hides under B-load+MFMA) ----
        float xn0 = xw0, xn1 = xw1, dn0 = dc0, dn1 = dc1;
        if (w == 7 && t + 1 < TT) {
            const size_t nx = (size_t)(t + 1) * (BB * HH) + (size_t)eb * HH + gch;
            const float2 xv = *(const float2*)&out[nx];
            const float2 dv = *(const float2*)&decay[nx];
            xn0 = xv.x; xn1 = xv.y; dn0 = dv.x; dn1 = dv.y;
        }

        // ---- B fragments: direct IF$ loads (no retry — sentinel guarantees) ----
        f16x8 bf0, bf1, bf2, bf3;
        if (t == 0) {
            f16x8 tmp[4];
#pragma unroll
            for (int s = 0; s < 4; ++s) {
                const float* hq = &h0[(size_t)bcol * HH + w * 128 + s * 32 + kg * 8];
                const f32x4 v0 = *(const f32x4*)hq;
                const f32x4 v1 = *(const f32x4*)(hq + 4);
                f16x8 b;
#pragma unroll
                for (int e = 0; e < 4; ++e) { b[e] = (_Float16)v0[e]; b[e + 4] = (_Float16)v1[e]; }
                tmp[s] = b;
            }
            bf0 = tmp[0]; bf1 = tmp[1]; bf2 = tmp[2]; bf3 = tmp[3];
        } else {
            const u64 hb = (u64)hdata
                         + (u64)(((t - 1) & 1) * (BB * HH) + bcol * HH + w * 128 + kg * 8) * 2;
            asm volatile(
                "global_load_dwordx4 %0, %4, off sc0 sc1\n\t"
                "global_load_dwordx4 %1, %4, off offset:64 sc0 sc1\n\t"
                "global_load_dwordx4 %2, %4, off offset:128 sc0 sc1\n\t"
                "global_load_dwordx4 %3, %4, off offset:192 sc0 sc1\n\t"
                "s_waitcnt vmcnt(0)"
                : "=&v"(bf0), "=&v"(bf1), "=&v"(bf2), "=&v"(bf3)
                : "v"(hb) : "memory");
            __builtin_amdgcn_sched_barrier(0);
        }

        // ---- 4 MFMAs: C[16ch x 8batch] partial over this wave's K-slice ----
        f32x4 acc = {0.f, 0.f, 0.f, 0.f};
        acc = __builtin_amdgcn_mfma_f32_16x16x32_f16(afrag[0], bf0, acc, 0, 0, 0);
        acc = __builtin_amdgcn_mfma_f32_16x16x32_f16(afrag[1], bf1, acc, 0, 0, 0);
        acc = __builtin_amdgcn_mfma_f32_16x16x32_f16(afrag[2], bf2, acc, 0, 0, 0);
        acc = __builtin_amdgcn_mfma_f32_16x16x32_f16(afrag[3], bf3, acc, 0, 0, 0);

        // C layout: col(batch)=lane&15, rows kg*4+jj in acc[jj]; cols 8-15 are dups
        if (ar < 8) *(f32x4*)&red[w][ar][kg * 4] = acc;
        __syncthreads();   // barrier 2: partials complete

        // ---- wave 7: sum 8 K-partials, pointwise, publish, release, sentinel ----
        if (w == 7) {
            float s0 = 0.f, s1 = 0.f;
#pragma unroll
            for (int ww = 0; ww < 8; ++ww) {
                const float2 rv = *(const float2*)&red[ww][eb][ec];
                s0 += rv.x; s1 += rv.y;
            }
            const float c0 = fast_tanh(s0 + xw0);
            const float c1 = fast_tanh(s1 + xw1);
            const float h0n = dc0 * hp0 + (1.0f - dc0) * c0;
            const float h1n = dc1 * hp1 + (1.0f - dc1) * c1;
            hp0 = h0n; hp1 = h1n;
            const u32 pk = f16bits(h0n) | (f16bits(h1n) << 16);
            const u64 dst = (u64)hdata + (u64)((t & 1) * (BB * HH) + eb * HH + gch) * 2;
            asm volatile("global_store_dword %0, %1, off sc0 sc1"
                         :: "v"(dst), "v"(pk) : "memory");
            *(float2*)&out[(size_t)t * (BB * HH) + (size_t)eb * HH + gch] =
                make_float2(h0n, h1n);
            asm volatile("s_waitcnt vmcnt(0)" ::: "memory");   // release: data ACK'd
            if (l == 0) {
                const u64 sp = (u64)(sent + j);
                const u32 tv = (u32)(t + 1);
                asm volatile("global_store_dword %0, %1, off sc0 sc1"
                             :: "v"(sp), "v"(tv) : "memory");
            }
        }
        xw0 = xn0; xw1 = xn1; dc0 = dn0; dc1 = dn1;
    }
}

// ---------------- launch ----------------
extern "C" void kernel_launch(void* const* d_in, const int* in_sizes, int n_in,
                              void* d_out, int out_size, void* d_ws, size_t ws_size,
                              hipStream_t stream) {
    const float* x    = (const float*)d_in[0];
    const float* h0   = (const float*)d_in[1];
    const float* Wx   = (const float*)d_in[2];
    const float* R    = (const float*)d_in[3];
    const float* bias = (const float*)d_in[4];
    const float* Wd   = (const float*)d_in[5];
    const float* bdel = (const float*)d_in[6];
    float* out = (float*)d_out;

    float* decay = (float*)d_ws;                                  // 64 MiB
    u16* hdata = (u16*)((char*)d_ws + (size_t)TT * BB * HH * 4);  // 2 x 16 KiB ping-pong
    u32* sent = (u32*)((char*)hdata + 2 * BB * HH * 2);           // 64 sentinels

    clear_sent_kernel<<<1, 64, 0, stream>>>(sent);
    proj_kernel<<<dim3(HH / 64, (TT * BB) / 64), 256, 0, stream>>>(
        x, Wx, Wd, bias, bdel, out, decay);
    scan_kernel<<<NBLK, 512, 0, stream>>>(h0, R, decay, out, hdata, sent);
}

// Round 12
// 4219.271 us; speedup vs baseline: 2.2271x; 2.2271x over previous
//
#include <hip/hip_runtime.h>

#define TT 2048
#define BB 8
#define DD 1024
#define HH 1024
#define CHB 128   // channels per block

typedef unsigned int u32;
typedef unsigned short u16;
typedef unsigned long long u64;
typedef float f32x4 __attribute__((ext_vector_type(4)));
typedef u32 u32x2 __attribute__((ext_vector_type(2)));
typedef _Float16 f16x8 __attribute__((ext_vector_type(8)));

static __device__ __forceinline__ u16 f16bits(float x) {
    _Float16 h = (_Float16)x;
    u16 r;
    __builtin_memcpy(&r, &h, 2);
    return r;
}

// fast tanh: sign(x) * (1 - e^{-2|x|}) / (1 + e^{-2|x|}), exp2-based
static __device__ __forceinline__ float fast_tanh(float x) {
    const float ax = __builtin_fabsf(x);
    const float e = __builtin_amdgcn_exp2f(ax * -2.885390082f);
    const float r = (1.0f - e) * __builtin_amdgcn_rcpf(1.0f + e);
    return __builtin_copysignf(r, x);
}

// ---------------- tag invalidation (every launch: no cross-call state) ----------------
__global__ __launch_bounds__(256) void clear_hb_kernel(u32* hb) {
    const int i = blockIdx.x * 256 + threadIdx.x;   // 64 x 256 = 16384 granules
    __hip_atomic_store(&hb[i], 0xFFFF0000u, __ATOMIC_RELAXED, __HIP_MEMORY_SCOPE_AGENT);
}

// ---------------- fused projection GEMMs via MFMA fp16 (unchanged) ----------------
__global__ __launch_bounds__(256) void proj_kernel(
    const float* __restrict__ x, const float* __restrict__ Wx,
    const float* __restrict__ Wd, const float* __restrict__ bias,
    const float* __restrict__ bdel, float* __restrict__ xw_out,
    float* __restrict__ decay_out)
{
    __shared__ __align__(16) _Float16 xs[64][40];
    __shared__ __align__(16) _Float16 wxs[64][40];
    __shared__ __align__(16) _Float16 wds[64][40];

    const int tid = threadIdx.x;
    const int bm = blockIdx.y * 64;
    const int bn = blockIdx.x * 64;
    const int w = tid >> 6, l = tid & 63;
    const int ar = l & 15, kg = l >> 4;
    const int srow = tid >> 2, scol = (tid & 3) * 8;

    f32x4 accx[4], accd[4];
#pragma unroll
    for (int ct = 0; ct < 4; ++ct) {
        accx[ct] = (f32x4){0.f, 0.f, 0.f, 0.f};
        accd[ct] = (f32x4){0.f, 0.f, 0.f, 0.f};
    }

    for (int k0 = 0; k0 < DD; k0 += 32) {
        const float* xp = &x[(size_t)(bm + srow) * DD + k0 + scol];
        const float* wxp = &Wx[(size_t)(bn + srow) * DD + k0 + scol];
        const float* wdp = &Wd[(size_t)(bn + srow) * DD + k0 + scol];
        f32x4 a0 = *(const f32x4*)xp,  a1 = *(const f32x4*)(xp + 4);
        f32x4 b0 = *(const f32x4*)wxp, b1 = *(const f32x4*)(wxp + 4);
        f32x4 c0 = *(const f32x4*)wdp, c1 = *(const f32x4*)(wdp + 4);
        f16x8 ha, hb_, hc;
#pragma unroll
        for (int e = 0; e < 4; ++e) {
            ha[e] = (_Float16)a0[e];  ha[e + 4] = (_Float16)a1[e];
            hb_[e] = (_Float16)b0[e]; hb_[e + 4] = (_Float16)b1[e];
            hc[e] = (_Float16)c0[e];  hc[e + 4] = (_Float16)c1[e];
        }
        __syncthreads();
        *(f16x8*)&xs[srow][scol] = ha;
        *(f16x8*)&wxs[srow][scol] = hb_;
        *(f16x8*)&wds[srow][scol] = hc;
        __syncthreads();

        const f16x8 af = *(const f16x8*)&xs[w * 16 + ar][kg * 8];
#pragma unroll
        for (int ct = 0; ct < 4; ++ct) {
            const f16x8 bfx = *(const f16x8*)&wxs[ct * 16 + ar][kg * 8];
            const f16x8 bfd = *(const f16x8*)&wds[ct * 16 + ar][kg * 8];
            accx[ct] = __builtin_amdgcn_mfma_f32_16x16x32_f16(af, bfx, accx[ct], 0, 0, 0);
            accd[ct] = __builtin_amdgcn_mfma_f32_16x16x32_f16(af, bfd, accd[ct], 0, 0, 0);
        }
    }

#pragma unroll
    for (int ct = 0; ct < 4; ++ct) {
        const int col = bn + ct * 16 + ar;
        const float bx = bias[col];
        const float bd = bdel[col];
#pragma unroll
        for (int jj = 0; jj < 4; ++jj) {
            const int row = bm + w * 16 + kg * 4 + jj;
            xw_out[(size_t)row * HH + col] = accx[ct][jj] + bx;
            decay_out[(size_t)row * HH + col] = 1.0f / (1.0f + expf(accd[ct][jj] + bd));
        }
    }
}

// ---------------- sequential scan: R8 + cross-step poll prefetch + counted waits ----------------
// 64 blocks x 512 threads (8 waves). Block (b=blk&7, g=blk>>3) owns channels
// [g*128,+128) of batch b; groups of 8 self-pace (tail = max-of-8).
// Tag-in-data granules {tag16|fp16}; shared strip hst[2][1024]; one barrier/step;
// wave w owns 16 channels x full K (no cross-wave reduce).
// NEW vs R8:
//  (1) both poll slots for step t+1 are ISSUED AT THE END of step t (addresses
//      known) -> the first check at loop top is nearly free; peer commits land
//      ~300-600 cyc after our epilogue, so the prefetched sample usually hits.
//  (2) counted vmcnt waits via younger-op arithmetic: slots are issued BEFORE
//      the epilogue stores, so slot readiness = vmcnt(3) (3 younger ops:
//      other slot + 2 stores), round-0 checks are 3,3, steady-state 1,1.
//      Store ACKs never gate the poll path; the stale-slot drain moved to the
//      end of the step (free); no post-discovery vmcnt(0).
__global__ __launch_bounds__(512) void scan_kernel(
    const float* __restrict__ h0, const float* __restrict__ R,
    const float* __restrict__ decay, float* __restrict__ out,
    u32* __restrict__ hb)
{
    __shared__ __align__(16) _Float16 hst[2][HH];   // ping-pong strip, 4 KB

    const int tid = threadIdx.x;
    const int w = tid >> 6;
    const int l = tid & 63;
    const int ar = l & 15, kg = l >> 4;
    const int b = blockIdx.x & 7, g = blockIdx.x >> 3;

    // ---- one-time A fragments: R row (one channel) x full K, 128 VGPRs ----
    const int chrow = g * CHB + w * 16 + ar;
    f16x8 afrag[32];
#pragma unroll
    for (int s = 0; s < 32; ++s) {
        const float* rp = &R[(size_t)chrow * HH + s * 32 + kg * 8];
        const f32x4 r0 = *(const f32x4*)rp;
        const f32x4 r1 = *(const f32x4*)(rp + 4);
        f16x8 a;
#pragma unroll
        for (int e = 0; e < 4; ++e) { a[e] = (_Float16)r0[e]; a[e + 4] = (_Float16)r1[e]; }
        afrag[s] = a;
    }

    const bool pollme = ((tid >> 6) != g);

    // epilogue lanes: ar<4 handle channel w*16 + kg*4 + ar via acc component ar
    const bool ep = (ar < 4);
    const int ch = g * CHB + w * 16 + kg * 4 + ar;     // valid when ep
    const int chloc = w * 16 + kg * 4 + ar;
    float hp = 0.f, xw_c = 0.f, d_c = 0.f;
    if (ep) {
        hp = h0[(size_t)b * HH + ch];
        xw_c = out[(size_t)b * HH + ch];     // row 0 projection (still intact)
        d_c = decay[(size_t)b * HH + ch];
    }

    u32x2 pA, pB;   // persistent poll slots (issued at end of previous step)

    for (int t = 0; t < TT; ++t) {
        const int p = t & 1;
        // ---- fill strip p ----
        if (t == 0) {
            const float2 v = *(const float2*)&h0[(size_t)b * HH + tid * 2];
            *(u32*)&hst[0][tid * 2] = (u32)f16bits(v.x) | ((u32)f16bits(v.y) << 16);
        } else if (pollme) {
            const u32 expt = (u32)(t - 1) << 16;
            const u64 gp = (u64)hb
                         + (u64)(((t - 1) & 1) * (BB * HH) + b * HH + tid * 2) * 4;
            u32x2 gr;
            int round = 0;
            while (true) {
                if (round == 0) { asm volatile("s_waitcnt vmcnt(3)" ::: "memory"); }
                else            { asm volatile("s_waitcnt vmcnt(1)" ::: "memory"); }
                __builtin_amdgcn_sched_barrier(0);
                if (!(((pA[0] ^ expt) | (pA[1] ^ expt)) & 0xffff0000u)) { gr = pA; break; }
                asm volatile("global_load_dwordx2 %0, %1, off sc0 sc1"
                             : "=v"(pA) : "v"(gp));
                if (round == 0) { asm volatile("s_waitcnt vmcnt(3)" ::: "memory"); }
                else            { asm volatile("s_waitcnt vmcnt(1)" ::: "memory"); }
                __builtin_amdgcn_sched_barrier(0);
                if (!(((pB[0] ^ expt) | (pB[1] ^ expt)) & 0xffff0000u)) { gr = pB; break; }
                asm volatile("global_load_dwordx2 %0, %1, off sc0 sc1"
                             : "=v"(pB) : "v"(gp));
                round = 1;
            }
            *(u32*)&hst[p][tid * 2] = (gr[0] & 0xffffu) | (gr[1] << 16);
        }
        __syncthreads();   // strip p complete (poll writes + prev epilogue's own-range)

        // ---- prefetch NEXT step's xw/decay EARLY (retires during MFMA) ----
        float xw_n = xw_c, d_n = d_c;
        if (ep && t + 1 < TT) {
            const size_t nidx = (size_t)(t + 1) * (BB * HH) + (size_t)b * HH + ch;
            xw_n = out[nidx];
            d_n = decay[nidx];
        }
        __builtin_amdgcn_sched_barrier(0);   // pin: xw loads issue before MFMA block

        // ---- 32 MFMAs (full K), 4 interleaved chains ----
        f32x4 ac0 = {0.f, 0.f, 0.f, 0.f}, ac1 = ac0, ac2 = ac0, ac3 = ac0;
#pragma unroll
        for (int s = 0; s < 32; s += 4) {
            ac0 = __builtin_amdgcn_mfma_f32_16x16x32_f16(
                      afrag[s + 0], *(const f16x8*)&hst[p][(s + 0) * 32 + kg * 8], ac0, 0, 0, 0);
            ac1 = __builtin_amdgcn_mfma_f32_16x16x32_f16(
                      afrag[s + 1], *(const f16x8*)&hst[p][(s + 1) * 32 + kg * 8], ac1, 0, 0, 0);
            ac2 = __builtin_amdgcn_mfma_f32_16x16x32_f16(
                      afrag[s + 2], *(const f16x8*)&hst[p][(s + 2) * 32 + kg * 8], ac2, 0, 0, 0);
            ac3 = __builtin_amdgcn_mfma_f32_16x16x32_f16(
                      afrag[s + 3], *(const f16x8*)&hst[p][(s + 3) * 32 + kg * 8], ac3, 0, 0, 0);
        }
        const f32x4 acc = (ac0 + ac1) + (ac2 + ac3);

        // ---- epilogue compute (no stores yet) ----
        float hnew = 0.f;
        u32 gran = 0;
        u16 hbits = 0;
        if (ep) {
            const float s = (ar == 0) ? acc[0] : (ar == 1) ? acc[1]
                          : (ar == 2) ? acc[2] : acc[3];
            const float cand = fast_tanh(s + xw_c);
            hnew = d_c * hp + (1.0f - d_c) * cand;
            hp = hnew;
            hbits = f16bits(hnew);
            gran = ((u32)t << 16) | (u32)hbits;
        }

        // ---- drain stale slot (free: issued >=1 phase ago), then prefetch, then stores ----
        asm volatile("s_waitcnt vmcnt(0)" ::: "memory");
        __builtin_amdgcn_sched_barrier(0);
        if (pollme && t + 1 < TT) {
            // step t+1 polls tag t in buffer (t&1)
            const u64 gpn = (u64)hb + (u64)((t & 1) * (BB * HH) + b * HH + tid * 2) * 4;
            asm volatile(
                "global_load_dwordx2 %0, %2, off sc0 sc1\n\t"
                "global_load_dwordx2 %1, %2, off sc0 sc1"
                : "=v"(pA), "=v"(pB) : "v"(gpn));
        }
        __builtin_amdgcn_sched_barrier(0);   // pin: slots issued BEFORE the stores
        if (ep) {
            const u64 dst = (u64)hb + (u64)((t & 1) * (BB * HH) + b * HH + ch) * 4;
            asm volatile("global_store_dword %0, %1, off sc0 sc1"
                         :: "v"(dst), "v"(gran) : "memory");
            hst[p ^ 1][g * CHB + chloc] = *(const _Float16*)&hbits;  // own-range shortcut
            out[(size_t)t * (BB * HH) + (size_t)b * HH + ch] = hnew;
        }
        xw_c = xw_n;
        d_c = d_n;
    }
}

// ---------------- launch ----------------
extern "C" void kernel_launch(void* const* d_in, const int* in_sizes, int n_in,
                              void* d_out, int out_size, void* d_ws, size_t ws_size,
                              hipStream_t stream) {
    const float* x    = (const float*)d_in[0];
    const float* h0   = (const float*)d_in[1];
    const float* Wx   = (const float*)d_in[2];
    const float* R    = (const float*)d_in[3];
    const float* bias = (const float*)d_in[4];
    const float* Wd   = (const float*)d_in[5];
    const float* bdel = (const float*)d_in[6];
    float* out = (float*)d_out;

    float* decay = (float*)d_ws;                                 // 64 MiB
    u32* hb = (u32*)((char*)d_ws + (size_t)TT * BB * HH * 4);    // 2 x 32 KiB ping-pong

    clear_hb_kernel<<<64, 256, 0, stream>>>(hb);
    proj_kernel<<<dim3(HH / 64, (TT * BB) / 64), 256, 0, stream>>>(
        x, Wx, Wd, bias, bdel, out, decay);
    scan_kernel<<<64, 512, 0, stream>>>(h0, R, decay, out, hb);
}

// Round 13
// 3391.547 us; speedup vs baseline: 2.7706x; 1.2441x over previous
//
#include <hip/hip_runtime.h>

#define TT 2048
#define BB 8
#define DD 1024
#define HH 1024
#define CHB 128   // channels per block

typedef unsigned int u32;
typedef unsigned short u16;
typedef unsigned long long u64;
typedef float f32x4 __attribute__((ext_vector_type(4)));
typedef u32 u32x2 __attribute__((ext_vector_type(2)));
typedef _Float16 f16x8 __attribute__((ext_vector_type(8)));

static __device__ __forceinline__ u16 f16bits(float x) {
    _Float16 h = (_Float16)x;
    u16 r;
    __builtin_memcpy(&r, &h, 2);
    return r;
}

// fast tanh: sign(x) * (1 - e^{-2|x|}) / (1 + e^{-2|x|}), exp2-based
static __device__ __forceinline__ float fast_tanh(float x) {
    const float ax = __builtin_fabsf(x);
    const float e = __builtin_amdgcn_exp2f(ax * -2.885390082f);
    const float r = (1.0f - e) * __builtin_amdgcn_rcpf(1.0f + e);
    return __builtin_copysignf(r, x);
}

// ---------------- tag invalidation (every launch: no cross-call state) ----------------
__global__ __launch_bounds__(256) void clear_hb_kernel(u32* hb) {
    const int i = blockIdx.x * 256 + threadIdx.x;   // 64 x 256 = 16384 granules
    __hip_atomic_store(&hb[i], 0xFFFF0000u, __ATOMIC_RELAXED, __HIP_MEMORY_SCOPE_AGENT);
}

// ---------------- fused projection GEMMs via MFMA fp16 (unchanged) ----------------
__global__ __launch_bounds__(256) void proj_kernel(
    const float* __restrict__ x, const float* __restrict__ Wx,
    const float* __restrict__ Wd, const float* __restrict__ bias,
    const float* __restrict__ bdel, float* __restrict__ xw_out,
    float* __restrict__ decay_out)
{
    __shared__ __align__(16) _Float16 xs[64][40];
    __shared__ __align__(16) _Float16 wxs[64][40];
    __shared__ __align__(16) _Float16 wds[64][40];

    const int tid = threadIdx.x;
    const int bm = blockIdx.y * 64;
    const int bn = blockIdx.x * 64;
    const int w = tid >> 6, l = tid & 63;
    const int ar = l & 15, kg = l >> 4;
    const int srow = tid >> 2, scol = (tid & 3) * 8;

    f32x4 accx[4], accd[4];
#pragma unroll
    for (int ct = 0; ct < 4; ++ct) {
        accx[ct] = (f32x4){0.f, 0.f, 0.f, 0.f};
        accd[ct] = (f32x4){0.f, 0.f, 0.f, 0.f};
    }

    for (int k0 = 0; k0 < DD; k0 += 32) {
        const float* xp = &x[(size_t)(bm + srow) * DD + k0 + scol];
        const float* wxp = &Wx[(size_t)(bn + srow) * DD + k0 + scol];
        const float* wdp = &Wd[(size_t)(bn + srow) * DD + k0 + scol];
        f32x4 a0 = *(const f32x4*)xp,  a1 = *(const f32x4*)(xp + 4);
        f32x4 b0 = *(const f32x4*)wxp, b1 = *(const f32x4*)(wxp + 4);
        f32x4 c0 = *(const f32x4*)wdp, c1 = *(const f32x4*)(wdp + 4);
        f16x8 ha, hb_, hc;
#pragma unroll
        for (int e = 0; e < 4; ++e) {
            ha[e] = (_Float16)a0[e];  ha[e + 4] = (_Float16)a1[e];
            hb_[e] = (_Float16)b0[e]; hb_[e + 4] = (_Float16)b1[e];
            hc[e] = (_Float16)c0[e];  hc[e + 4] = (_Float16)c1[e];
        }
        __syncthreads();
        *(f16x8*)&xs[srow][scol] = ha;
        *(f16x8*)&wxs[srow][scol] = hb_;
        *(f16x8*)&wds[srow][scol] = hc;
        __syncthreads();

        const f16x8 af = *(const f16x8*)&xs[w * 16 + ar][kg * 8];
#pragma unroll
        for (int ct = 0; ct < 4; ++ct) {
            const f16x8 bfx = *(const f16x8*)&wxs[ct * 16 + ar][kg * 8];
            const f16x8 bfd = *(const f16x8*)&wds[ct * 16 + ar][kg * 8];
            accx[ct] = __builtin_amdgcn_mfma_f32_16x16x32_f16(af, bfx, accx[ct], 0, 0, 0);
            accd[ct] = __builtin_amdgcn_mfma_f32_16x16x32_f16(af, bfd, accd[ct], 0, 0, 0);
        }
    }

#pragma unroll
    for (int ct = 0; ct < 4; ++ct) {
        const int col = bn + ct * 16 + ar;
        const float bx = bias[col];
        const float bd = bdel[col];
#pragma unroll
        for (int jj = 0; jj < 4; ++jj) {
            const int row = bm + w * 16 + kg * 4 + jj;
            xw_out[(size_t)row * HH + col] = accx[ct][jj] + bx;
            decay_out[(size_t)row * HH + col] = 1.0f / (1.0f + expf(accd[ct][jj] + bd));
        }
    }
}

// 4-slot staggered poll; steady-state wait is uniformly vmcnt(3) (3 younger slot
// ops); older store-ACKs/stale slots drain once under the first wait (hidden by
// slot-0's round trip). NO post-break drain: leftover in-flight slots land into
// this parity's registers while the next step polls the other set.
#define POLL4(S0, S1, S2, S3)                                                      \
    asm volatile("global_load_dwordx2 %0, %1, off sc0 sc1" : "=v"(S0) : "v"(gp)); \
    __builtin_amdgcn_s_sleep(1);                                                   \
    asm volatile("global_load_dwordx2 %0, %1, off sc0 sc1" : "=v"(S1) : "v"(gp)); \
    __builtin_amdgcn_s_sleep(1);                                                   \
    asm volatile("global_load_dwordx2 %0, %1, off sc0 sc1" : "=v"(S2) : "v"(gp)); \
    __builtin_amdgcn_s_sleep(1);                                                   \
    asm volatile("global_load_dwordx2 %0, %1, off sc0 sc1" : "=v"(S3) : "v"(gp)); \
    while (true) {                                                                 \
        asm volatile("s_waitcnt vmcnt(3)" ::: "memory");                           \
        __builtin_amdgcn_sched_barrier(0);                                         \
        if (!(((S0[0] ^ expt) | (S0[1] ^ expt)) & 0xffff0000u)) { gr = S0; break; }\
        asm volatile("global_load_dwordx2 %0, %1, off sc0 sc1" : "=v"(S0) : "v"(gp)); \
        asm volatile("s_waitcnt vmcnt(3)" ::: "memory");                           \
        __builtin_amdgcn_sched_barrier(0);                                         \
        if (!(((S1[0] ^ expt) | (S1[1] ^ expt)) & 0xffff0000u)) { gr = S1; break; }\
        asm volatile("global_load_dwordx2 %0, %1, off sc0 sc1" : "=v"(S1) : "v"(gp)); \
        asm volatile("s_waitcnt vmcnt(3)" ::: "memory");                           \
        __builtin_amdgcn_sched_barrier(0);                                         \
        if (!(((S2[0] ^ expt) | (S2[1] ^ expt)) & 0xffff0000u)) { gr = S2; break; }\
        asm volatile("global_load_dwordx2 %0, %1, off sc0 sc1" : "=v"(S2) : "v"(gp)); \
        asm volatile("s_waitcnt vmcnt(3)" ::: "memory");                           \
        __builtin_amdgcn_sched_barrier(0);                                         \
        if (!(((S3[0] ^ expt) | (S3[1] ^ expt)) & 0xffff0000u)) { gr = S3; break; }\
        asm volatile("global_load_dwordx2 %0, %1, off sc0 sc1" : "=v"(S3) : "v"(gp)); \
    }

// ---------------- sequential scan: R8 + 4-slot parity-ping-pong poll ----------------
// 64 blocks x 512 threads (8 waves). Block (b=blk&7, g=blk>>3) owns channels
// [g*128,+128) of batch b; groups of 8 self-pace (tail = max-of-8).
// Tag-in-data granules {tag16|fp16}; shared strip hst[2][1024]; one barrier/step;
// wave w owns 16 channels x full K (no cross-wave reduce). Protocol induction
// identical to R8 (block stores tag t only after block-wide poll of t-1).
__global__ __launch_bounds__(512) void scan_kernel(
    const float* __restrict__ h0, const float* __restrict__ R,
    const float* __restrict__ decay, float* __restrict__ out,
    u32* __restrict__ hb)
{
    __shared__ __align__(16) _Float16 hst[2][HH];   // ping-pong strip, 4 KB

    const int tid = threadIdx.x;
    const int w = tid >> 6;
    const int l = tid & 63;
    const int ar = l & 15, kg = l >> 4;
    const int b = blockIdx.x & 7, g = blockIdx.x >> 3;

    // ---- one-time A fragments: R row (one channel) x full K, 128 VGPRs ----
    const int chrow = g * CHB + w * 16 + ar;
    f16x8 afrag[32];
#pragma unroll
    for (int s = 0; s < 32; ++s) {
        const float* rp = &R[(size_t)chrow * HH + s * 32 + kg * 8];
        const f32x4 r0 = *(const f32x4*)rp;
        const f32x4 r1 = *(const f32x4*)(rp + 4);
        f16x8 a;
#pragma unroll
        for (int e = 0; e < 4; ++e) { a[e] = (_Float16)r0[e]; a[e + 4] = (_Float16)r1[e]; }
        afrag[s] = a;
    }

    const bool pollme = ((tid >> 6) != g);

    // epilogue lanes: ar<4 handle channel w*16 + kg*4 + ar via acc component ar
    const bool ep = (ar < 4);
    const int ch = g * CHB + w * 16 + kg * 4 + ar;     // valid when ep
    const int chloc = w * 16 + kg * 4 + ar;
    float hp = 0.f, xw_c = 0.f, d_c = 0.f;
    if (ep) {
        hp = h0[(size_t)b * HH + ch];
        xw_c = out[(size_t)b * HH + ch];     // row 0 projection (still intact)
        d_c = decay[(size_t)b * HH + ch];
    }

    // two poll-slot register sets, alternated by step parity (static names — no
    // runtime-indexed arrays, rule #20)
    u32x2 sA0, sA1, sA2, sA3, sB0, sB1, sB2, sB3;

    for (int t = 0; t < TT; ++t) {
        const int p = t & 1;
        // ---- fill strip p ----
        if (t == 0) {
            const float2 v = *(const float2*)&h0[(size_t)b * HH + tid * 2];
            *(u32*)&hst[0][tid * 2] = (u32)f16bits(v.x) | ((u32)f16bits(v.y) << 16);
        } else if (pollme) {
            const u32 expt = (u32)(t - 1) << 16;
            const u64 gp = (u64)hb
                         + (u64)(((t - 1) & 1) * (BB * HH) + b * HH + tid * 2) * 4;
            u32x2 gr;
            if (p == 0) { POLL4(sA0, sA1, sA2, sA3) }
            else        { POLL4(sB0, sB1, sB2, sB3) }
            *(u32*)&hst[p][tid * 2] = (gr[0] & 0xffffu) | (gr[1] << 16);
        }
        __syncthreads();   // strip p complete (poll writes + prev epilogue's own-range)

        // ---- prefetch NEXT step's xw/decay (hides under this step) ----
        float xw_n = xw_c, d_n = d_c;
        if (ep && t + 1 < TT) {
            const size_t nidx = (size_t)(t + 1) * (BB * HH) + (size_t)b * HH + ch;
            xw_n = out[nidx];
            d_n = decay[nidx];
        }

        // ---- 32 MFMAs (full K), 4 interleaved chains ----
        f32x4 ac0 = {0.f, 0.f, 0.f, 0.f}, ac1 = ac0, ac2 = ac0, ac3 = ac0;
#pragma unroll
        for (int s = 0; s < 32; s += 4) {
            ac0 = __builtin_amdgcn_mfma_f32_16x16x32_f16(
                      afrag[s + 0], *(const f16x8*)&hst[p][(s + 0) * 32 + kg * 8], ac0, 0, 0, 0);
            ac1 = __builtin_amdgcn_mfma_f32_16x16x32_f16(
                      afrag[s + 1], *(const f16x8*)&hst[p][(s + 1) * 32 + kg * 8], ac1, 0, 0, 0);
            ac2 = __builtin_amdgcn_mfma_f32_16x16x32_f16(
                      afrag[s + 2], *(const f16x8*)&hst[p][(s + 2) * 32 + kg * 8], ac2, 0, 0, 0);
            ac3 = __builtin_amdgcn_mfma_f32_16x16x32_f16(
                      afrag[s + 3], *(const f16x8*)&hst[p][(s + 3) * 32 + kg * 8], ac3, 0, 0, 0);
        }
        const f32x4 acc = (ac0 + ac1) + (ac2 + ac3);

        // ---- epilogue: broadcast FIRST (critical path), then private out store ----
        if (ep) {
            const float s = (ar == 0) ? acc[0] : (ar == 1) ? acc[1]
                          : (ar == 2) ? acc[2] : acc[3];
            const float cand = fast_tanh(s + xw_c);
            const float hnew = d_c * hp + (1.0f - d_c) * cand;
            hp = hnew;
            const u16 hbits = f16bits(hnew);
            const u32 gran = ((u32)t << 16) | (u32)hbits;
            const u64 dst = (u64)hb + (u64)((t & 1) * (BB * HH) + b * HH + ch) * 4;
            asm volatile("global_store_dword %0, %1, off sc0 sc1"
                         :: "v"(dst), "v"(gran) : "memory");
            hst[p ^ 1][g * CHB + chloc] = *(const _Float16*)&hbits;  // own-range shortcut
            out[(size_t)t * (BB * HH) + (size_t)b * HH + ch] = hnew;
        }
        xw_c = xw_n;
        d_c = d_n;
    }
}

// ---------------- launch ----------------
extern "C" void kernel_launch(void* const* d_in, const int* in_sizes, int n_in,
                              void* d_out, int out_size, void* d_ws, size_t ws_size,
                              hipStream_t stream) {
    const float* x    = (const float*)d_in[0];
    const float* h0   = (const float*)d_in[1];
    const float* Wx   = (const float*)d_in[2];
    const float* R    = (const float*)d_in[3];
    const float* bias = (const float*)d_in[4];
    const float* Wd   = (const float*)d_in[5];
    const float* bdel = (const float*)d_in[6];
    float* out = (float*)d_out;

    float* decay = (float*)d_ws;                                 // 64 MiB
    u32* hb = (u32*)((char*)d_ws + (size_t)TT * BB * HH * 4);    // 2 x 32 KiB ping-pong

    clear_hb_kernel<<<64, 256, 0, stream>>>(hb);
    proj_kernel<<<dim3(HH / 64, (TT * BB) / 64), 256, 0, stream>>>(
        x, Wx, Wd, bias, bdel, out, decay);
    scan_kernel<<<64, 512, 0, stream>>>(h0, R, decay, out, hb);
}

// Round 14
// 3252.535 us; speedup vs baseline: 2.8891x; 1.0427x over previous
//
#include <hip/hip_runtime.h>

#define TT 2048
#define BB 8
#define DD 1024
#define HH 1024
#define CHB 128   // channels per block

typedef unsigned int u32;
typedef unsigned short u16;
typedef unsigned long long u64;
typedef float f32x4 __attribute__((ext_vector_type(4)));
typedef u32 u32x2 __attribute__((ext_vector_type(2)));
typedef _Float16 f16x8 __attribute__((ext_vector_type(8)));

static __device__ __forceinline__ u16 f16bits(float x) {
    _Float16 h = (_Float16)x;
    u16 r;
    __builtin_memcpy(&r, &h, 2);
    return r;
}

// fast tanh: tanh(x) = sign(x) * (1 - e^{-2|x|}) / (1 + e^{-2|x|}), exp2-based
static __device__ __forceinline__ float fast_tanh(float x) {
    const float ax = __builtin_fabsf(x);
    const float e = __builtin_amdgcn_exp2f(ax * -2.885390082f);   // 2^(-2|x|*log2e)
    const float r = (1.0f - e) * __builtin_amdgcn_rcpf(1.0f + e);
    return __builtin_copysignf(r, x);
}

// ---------------- tag invalidation (every launch: no cross-call state) ----------------
__global__ __launch_bounds__(256) void clear_hb_kernel(u32* hb) {
    const int i = blockIdx.x * 256 + threadIdx.x;   // 64 x 256 = 16384 granules
    __hip_atomic_store(&hb[i], 0xFFFF0000u, __ATOMIC_RELAXED, __HIP_MEMORY_SCOPE_AGENT);
}

// ---------------- fused projection GEMMs via MFMA fp16 ----------------
__global__ __launch_bounds__(256) void proj_kernel(
    const float* __restrict__ x, const float* __restrict__ Wx,
    const float* __restrict__ Wd, const float* __restrict__ bias,
    const float* __restrict__ bdel, float* __restrict__ xw_out,
    float* __restrict__ decay_out)
{
    __shared__ __align__(16) _Float16 xs[64][40];
    __shared__ __align__(16) _Float16 wxs[64][40];
    __shared__ __align__(16) _Float16 wds[64][40];

    const int tid = threadIdx.x;
    const int bm = blockIdx.y * 64;
    const int bn = blockIdx.x * 64;
    const int w = tid >> 6, l = tid & 63;
    const int ar = l & 15, kg = l >> 4;
    const int srow = tid >> 2, scol = (tid & 3) * 8;

    f32x4 accx[4], accd[4];
#pragma unroll
    for (int ct = 0; ct < 4; ++ct) {
        accx[ct] = (f32x4){0.f, 0.f, 0.f, 0.f};
        accd[ct] = (f32x4){0.f, 0.f, 0.f, 0.f};
    }

    for (int k0 = 0; k0 < DD; k0 += 32) {
        const float* xp = &x[(size_t)(bm + srow) * DD + k0 + scol];
        const float* wxp = &Wx[(size_t)(bn + srow) * DD + k0 + scol];
        const float* wdp = &Wd[(size_t)(bn + srow) * DD + k0 + scol];
        f32x4 a0 = *(const f32x4*)xp,  a1 = *(const f32x4*)(xp + 4);
        f32x4 b0 = *(const f32x4*)wxp, b1 = *(const f32x4*)(wxp + 4);
        f32x4 c0 = *(const f32x4*)wdp, c1 = *(const f32x4*)(wdp + 4);
        f16x8 ha, hb_, hc;
#pragma unroll
        for (int e = 0; e < 4; ++e) {
            ha[e] = (_Float16)a0[e];  ha[e + 4] = (_Float16)a1[e];
            hb_[e] = (_Float16)b0[e]; hb_[e + 4] = (_Float16)b1[e];
            hc[e] = (_Float16)c0[e];  hc[e + 4] = (_Float16)c1[e];
        }
        __syncthreads();
        *(f16x8*)&xs[srow][scol] = ha;
        *(f16x8*)&wxs[srow][scol] = hb_;
        *(f16x8*)&wds[srow][scol] = hc;
        __syncthreads();

        const f16x8 af = *(const f16x8*)&xs[w * 16 + ar][kg * 8];
#pragma unroll
        for (int ct = 0; ct < 4; ++ct) {
            const f16x8 bfx = *(const f16x8*)&wxs[ct * 16 + ar][kg * 8];
            const f16x8 bfd = *(const f16x8*)&wds[ct * 16 + ar][kg * 8];
            accx[ct] = __builtin_amdgcn_mfma_f32_16x16x32_f16(af, bfx, accx[ct], 0, 0, 0);
            accd[ct] = __builtin_amdgcn_mfma_f32_16x16x32_f16(af, bfd, accd[ct], 0, 0, 0);
        }
    }

#pragma unroll
    for (int ct = 0; ct < 4; ++ct) {
        const int col = bn + ct * 16 + ar;
        const float bx = bias[col];
        const float bd = bdel[col];
#pragma unroll
        for (int j = 0; j < 4; ++j) {
            const int row = bm + w * 16 + kg * 4 + j;
            xw_out[(size_t)row * HH + col] = accx[ct][j] + bx;
            decay_out[(size_t)row * HH + col] = 1.0f / (1.0f + expf(accd[ct][j] + bd));
        }
    }
}

// ---------------- sequential scan: shared strip, staggered double-poll (R8) ----------------
// 64 blocks x 512 threads (8 waves). Block (b=blk&7, g=blk>>3) owns channels
// [g*128,+128) of batch b. One shared h strip per step (ping-pong hst[2][1024]);
// non-own threads poll one tagged dwordx2 {tag16|fp16} with TWO staggered
// outstanding loads; own range short-circuits via LDS. Single __syncthreads per
// step. Wave w owns 16 channels x full K=1024 (no cross-wave reduce).
// Protocol: block stores tag t only after block-wide poll of t-1 (barrier) =>
// ping-pong overwrite of tag t-2 is race-free.
__global__ __launch_bounds__(512) void scan_kernel(
    const float* __restrict__ h0, const float* __restrict__ R,
    const float* __restrict__ decay, float* __restrict__ out,
    u32* __restrict__ hb)
{
    __shared__ __align__(16) _Float16 hst[2][HH];   // ping-pong strip, 4 KB

    const int tid = threadIdx.x;
    const int w = tid >> 6;
    const int l = tid & 63;
    const int ar = l & 15, kg = l >> 4;
    const int b = blockIdx.x & 7, g = blockIdx.x >> 3;

    // ---- one-time A fragments: R row (one channel) x full K, 128 VGPRs ----
    const int chrow = g * CHB + w * 16 + ar;
    f16x8 afrag[32];
#pragma unroll
    for (int s = 0; s < 32; ++s) {
        const float* rp = &R[(size_t)chrow * HH + s * 32 + kg * 8];
        const f32x4 r0 = *(const f32x4*)rp;
        const f32x4 r1 = *(const f32x4*)(rp + 4);
        f16x8 a;
#pragma unroll
        for (int e = 0; e < 4; ++e) { a[e] = (_Float16)r0[e]; a[e + 4] = (_Float16)r1[e]; }
        afrag[s] = a;
    }

    const bool pollme = ((tid >> 6) != g);

    // epilogue lanes: ar<4 handle channel w*16 + kg*4 + ar via acc component ar
    const bool ep = (ar < 4);
    const int ch = g * CHB + w * 16 + kg * 4 + ar;     // valid when ep
    const int chloc = w * 16 + kg * 4 + ar;
    float hp = 0.f, xw_c = 0.f, d_c = 0.f;
    if (ep) {
        hp = h0[(size_t)b * HH + ch];
        xw_c = out[(size_t)b * HH + ch];     // row 0 projection (still intact)
        d_c = decay[(size_t)b * HH + ch];
    }

    for (int t = 0; t < TT; ++t) {
        const int p = t & 1;
        // ---- fill strip p: staggered double-poll of remote granules ----
        if (t == 0) {
            const float2 v = *(const float2*)&h0[(size_t)b * HH + tid * 2];
            *(u32*)&hst[0][tid * 2] = (u32)f16bits(v.x) | ((u32)f16bits(v.y) << 16);
        } else if (pollme) {
            const u32 expt = (u32)(t - 1) << 16;
            const u64 gp = (u64)hb
                         + (u64)(((t - 1) & 1) * (BB * HH) + b * HH + tid * 2) * 4;
            u32x2 gA, gB, gr;
            asm volatile("global_load_dwordx2 %0, %1, off sc0 sc1"
                         : "=v"(gA) : "v"(gp));
            __builtin_amdgcn_s_sleep(4);   // ~256 cyc stagger between the two slots
            asm volatile("global_load_dwordx2 %0, %1, off sc0 sc1"
                         : "=v"(gB) : "v"(gp));
            while (true) {
                asm volatile("s_waitcnt vmcnt(1)" ::: "memory");   // slot A landed
                __builtin_amdgcn_sched_barrier(0);
                if (!(((gA[0] ^ expt) | (gA[1] ^ expt)) & 0xffff0000u)) { gr = gA; break; }
                asm volatile("global_load_dwordx2 %0, %1, off sc0 sc1"
                             : "=v"(gA) : "v"(gp));
                asm volatile("s_waitcnt vmcnt(1)" ::: "memory");   // slot B landed
                __builtin_amdgcn_sched_barrier(0);
                if (!(((gB[0] ^ expt) | (gB[1] ^ expt)) & 0xffff0000u)) { gr = gB; break; }
                asm volatile("global_load_dwordx2 %0, %1, off sc0 sc1"
                             : "=v"(gB) : "v"(gp));
            }
            // drain the still-outstanding slot before its register can be reused
            asm volatile("s_waitcnt vmcnt(0)" ::: "memory");
            __builtin_amdgcn_sched_barrier(0);
            *(u32*)&hst[p][tid * 2] = (gr[0] & 0xffffu) | (gr[1] << 16);
        }
        __syncthreads();   // strip p complete (poll writes + prev epilogue's own-range)

        // ---- prefetch NEXT step's xw/decay (hides under this step) ----
        float xw_n = xw_c, d_n = d_c;
        if (ep && t + 1 < TT) {
            const size_t nidx = (size_t)(t + 1) * (BB * HH) + (size_t)b * HH + ch;
            xw_n = out[nidx];
            d_n = decay[nidx];
        }

        // ---- 32 MFMAs (full K), 4 interleaved chains ----
        f32x4 ac0 = {0.f, 0.f, 0.f, 0.f}, ac1 = ac0, ac2 = ac0, ac3 = ac0;
#pragma unroll
        for (int s = 0; s < 32; s += 4) {
            ac0 = __builtin_amdgcn_mfma_f32_16x16x32_f16(
                      afrag[s + 0], *(const f16x8*)&hst[p][(s + 0) * 32 + kg * 8], ac0, 0, 0, 0);
            ac1 = __builtin_amdgcn_mfma_f32_16x16x32_f16(
                      afrag[s + 1], *(const f16x8*)&hst[p][(s + 1) * 32 + kg * 8], ac1, 0, 0, 0);
            ac2 = __builtin_amdgcn_mfma_f32_16x16x32_f16(
                      afrag[s + 2], *(const f16x8*)&hst[p][(s + 2) * 32 + kg * 8], ac2, 0, 0, 0);
            ac3 = __builtin_amdgcn_mfma_f32_16x16x32_f16(
                      afrag[s + 3], *(const f16x8*)&hst[p][(s + 3) * 32 + kg * 8], ac3, 0, 0, 0);
        }
        const f32x4 acc = (ac0 + ac1) + (ac2 + ac3);

        // ---- epilogue: broadcast FIRST (critical path), then private out store ----
        if (ep) {
            const float s = (ar == 0) ? acc[0] : (ar == 1) ? acc[1]
                          : (ar == 2) ? acc[2] : acc[3];
            const float cand = fast_tanh(s + xw_c);
            const float hnew = d_c * hp + (1.0f - d_c) * cand;
            hp = hnew;
            const u16 hbits = f16bits(hnew);
            const u32 gran = ((u32)t << 16) | (u32)hbits;
            const u64 dst = (u64)hb + (u64)((t & 1) * (BB * HH) + b * HH + ch) * 4;
            asm volatile("global_store_dword %0, %1, off sc0 sc1"
                         :: "v"(dst), "v"(gran) : "memory");
            hst[p ^ 1][g * CHB + chloc] = *(const _Float16*)&hbits;  // own-range shortcut
            out[(size_t)t * (BB * HH) + (size_t)b * HH + ch] = hnew;
        }
        xw_c = xw_n;
        d_c = d_n;
    }
}

// ---------------- launch ----------------
extern "C" void kernel_launch(void* const* d_in, const int* in_sizes, int n_in,
                              void* d_out, int out_size, void* d_ws, size_t ws_size,
                              hipStream_t stream) {
    const float* x    = (const float*)d_in[0];
    const float* h0   = (const float*)d_in[1];
    const float* Wx   = (const float*)d_in[2];
    const float* R    = (const float*)d_in[3];
    const float* bias = (const float*)d_in[4];
    const float* Wd   = (const float*)d_in[5];
    const float* bdel = (const float*)d_in[6];
    float* out = (float*)d_out;

    float* decay = (float*)d_ws;                                 // 64 MiB
    u32* hb = (u32*)((char*)d_ws + (size_t)TT * BB * HH * 4);    // 2 x 32 KiB ping-pong

    clear_hb_kernel<<<64, 256, 0, stream>>>(hb);
    proj_kernel<<<dim3(HH / 64, (TT * BB) / 64), 256, 0, stream>>>(
        x, Wx, Wd, bias, bdel, out, decay);
    scan_kernel<<<64, 512, 0, stream>>>(h0, R, decay, out, hb);
}